// Round 1
// baseline (805.084 us; speedup 1.0000x reference)
//
#include <hip/hip_runtime.h>
#include <math.h>

// Problem constants (from reference file)
constexpr int N_NODES  = 50000;
constexpr int N_EDGES  = 1600000;
constexpr int G_GRAPHS = 64;
constexpr int D        = 32;
constexpr int D_ATTR   = 16;
constexpr int N_RBF    = 8;

// rw(len) lookup table: 4096 intervals over [0, LMAX]; beyond LMAX all rbf ~ exp(-2.56*25) ~ 0
constexpr int   TBL      = 4096;
constexpr int   TBL_ROWS = TBL + 1;   // rows 0..TBL inclusive (lerp reads i0 and i0+1, i0 <= TBL-1)
constexpr float LMAX     = 10.0f;

__device__ __forceinline__ float silu(float x) {
    return x / (1.0f + __expf(-x));
}

// ---------------------------------------------------------------------------
// 1) Node init: x_attr = W_elem[x], h = x_attr @ W0 + b0
//    thread = (node, channel), 32 channels
// ---------------------------------------------------------------------------
__global__ void node_init_kernel(const int* __restrict__ x,
                                 const float* __restrict__ W_elem,
                                 const float* __restrict__ W0,
                                 const float* __restrict__ b0,
                                 float* __restrict__ x_attr,
                                 float* __restrict__ h) {
    int t = blockIdx.x * blockDim.x + threadIdx.x;
    int n = t >> 5, c = t & 31;
    if (n >= N_NODES) return;
    int sp = x[n];
    const float* we = W_elem + sp * D_ATTR;
    float acc = b0[c];
#pragma unroll
    for (int a = 0; a < D_ATTR; ++a) acc += we[a] * W0[a * D + c];
    h[n * D + c] = acc;
    if (c < D_ATTR) x_attr[n * D_ATTR + c] = we[c];
}

// ---------------------------------------------------------------------------
// 2) Degree histogram over dst
// ---------------------------------------------------------------------------
__global__ void count_kernel(const int* __restrict__ eidx, int* __restrict__ count) {
    int e = blockIdx.x * blockDim.x + threadIdx.x;
    if (e < N_EDGES) atomicAdd(&count[eidx[N_EDGES + e]], 1);
}

// ---------------------------------------------------------------------------
// 3) Exclusive scan (single block, thread-chunked) -> rowptr, cursor (=rowptr copy)
// ---------------------------------------------------------------------------
__global__ void scan_kernel(const int* __restrict__ count,
                            int* __restrict__ rowptr,
                            int* __restrict__ cursor) {
    constexpr int T = 1024;
    constexpr int CHUNK = (N_NODES + T - 1) / T;  // 49
    __shared__ int sums[T];
    int t = threadIdx.x;
    int beg = t * CHUNK;
    int local[CHUNK];
    int run = 0;
#pragma unroll
    for (int j = 0; j < CHUNK; ++j) {
        int i = beg + j;
        int v = (i < N_NODES) ? count[i] : 0;
        local[j] = run;
        run += v;
    }
    sums[t] = run;
    __syncthreads();
    for (int s = 1; s < T; s <<= 1) {
        int v = (t >= s) ? sums[t - s] : 0;
        __syncthreads();
        sums[t] += v;
        __syncthreads();
    }
    int prefix = (t == 0) ? 0 : sums[t - 1];
#pragma unroll
    for (int j = 0; j < CHUNK; ++j) {
        int i = beg + j;
        if (i < N_NODES) {
            int v = prefix + local[j];
            rowptr[i] = v;
            cursor[i] = v;
        }
    }
    if (t == T - 1) rowptr[N_NODES] = prefix + run;  // == N_EDGES
}

// ---------------------------------------------------------------------------
// 4) Edge geometry + CSR scatter: records {src, len, sh_w[3]} at CSR slots
// ---------------------------------------------------------------------------
__global__ void scatter_kernel(const int* __restrict__ eidx,
                               const float* __restrict__ pos,
                               const float* __restrict__ period,
                               const float* __restrict__ wsh,
                               int* __restrict__ cursor,
                               int* __restrict__ csr_src,
                               float* __restrict__ csr_len,
                               float* __restrict__ csr_shw) {
    int e = blockIdx.x * blockDim.x + threadIdx.x;
    if (e >= N_EDGES) return;
    int s = eidx[e];
    int d = eidx[N_EDGES + e];
    float vx = pos[d * 3 + 0] - pos[s * 3 + 0] + period[e * 3 + 0];
    float vy = pos[d * 3 + 1] - pos[s * 3 + 1] + period[e * 3 + 1];
    float vz = pos[d * 3 + 2] - pos[s * 3 + 2] + period[e * 3 + 2];
    float len = sqrtf(vx * vx + vy * vy + vz * vz);
    float inv = 1.0f / (len + 1e-9f);
    float ux = vx * inv, uy = vy * inv, uz = vz * inv;
    int k = atomicAdd(&cursor[d], 1);
    csr_src[k] = s;
    csr_len[k] = len;
#pragma unroll
    for (int l = 0; l < 3; ++l) {
        csr_shw[l * N_EDGES + k] =
            wsh[l * 4 + 0] + ux * wsh[l * 4 + 1] + uy * wsh[l * 4 + 2] + uz * wsh[l * 4 + 3];
    }
}

// ---------------------------------------------------------------------------
// 5) Build rw(len) tables for the 3 layers: table[l][idx][c]
//    rw = relu(rbf @ Wr1[l] + br1[l]) @ Wr2[l]
// ---------------------------------------------------------------------------
__global__ void table_kernel(const float* __restrict__ Wr1,
                             const float* __restrict__ br1,
                             const float* __restrict__ Wr2,
                             float* __restrict__ table) {
    int t = blockIdx.x * blockDim.x + threadIdx.x;
    if (t >= 3 * TBL_ROWS) return;
    int l = t / TBL_ROWS;
    int idx = t % TBL_ROWS;
    float len = (float)idx * (LMAX / (float)TBL);
    const float gamma = (8.0f / 5.0f) * (8.0f / 5.0f);  // (N_RBF/CUTOFF)^2
    float rbf[N_RBF];
#pragma unroll
    for (int k = 0; k < N_RBF; ++k) {
        float dd = len - (float)k * (5.0f / 7.0f);  // linspace(0, CUTOFF, 8)
        rbf[k] = __expf(-gamma * dd * dd);
    }
    float out[D];
#pragma unroll
    for (int c = 0; c < D; ++c) out[c] = 0.0f;
    for (int j = 0; j < D; ++j) {
        float z = br1[l * D + j];
#pragma unroll
        for (int k = 0; k < N_RBF; ++k) z += rbf[k] * Wr1[l * N_RBF * D + k * D + j];
        z = fmaxf(z, 0.0f);
        const float* w2 = Wr2 + l * D * D + j * D;
#pragma unroll
        for (int c = 0; c < D; ++c) out[c] += z * w2[c];
    }
    float* dst = table + ((size_t)(l * TBL_ROWS + idx)) * D;
#pragma unroll
    for (int c = 0; c < D; ++c) dst[c] = out[c];
}

// ---------------------------------------------------------------------------
// 6) hm = h @ Wmsg[l]   (thread = (node, channel))
// ---------------------------------------------------------------------------
__global__ void hm_kernel(int layer,
                          const float* __restrict__ h,
                          const float* __restrict__ Wmsg,
                          float* __restrict__ hm) {
    int t = blockIdx.x * blockDim.x + threadIdx.x;
    int n = t >> 5, c = t & 31;
    if (n >= N_NODES) return;
    const float* W = Wmsg + layer * D * D;
    const float* hrow = h + n * D;
    float acc = 0.0f;
#pragma unroll
    for (int j = 0; j < D; ++j) acc += hrow[j] * W[j * D + c];
    hm[n * D + c] = acc;
}

// ---------------------------------------------------------------------------
// 7) Conv layer: wave-per-node, channel-parallel; fused node update.
//    lane = {half, c}; half-waves each process one edge per iteration.
//    agg accumulated in registers -> h = silu(agg + x_attr@Wattr + h@Wself + bconv)
// ---------------------------------------------------------------------------
__global__ void conv_kernel(int layer,
                            const float* __restrict__ hm,
                            const float* __restrict__ csr_len,
                            const float* __restrict__ csr_shw,
                            const int* __restrict__ csr_src,
                            const int* __restrict__ rowptr,
                            const float* __restrict__ x_attr,
                            const float* __restrict__ table,
                            const float* __restrict__ Wattr,
                            const float* __restrict__ Wself,
                            const float* __restrict__ bconv,
                            float* __restrict__ h) {
    int gtid = blockIdx.x * blockDim.x + threadIdx.x;
    int node = gtid >> 6;
    if (node >= N_NODES) return;
    int lane = threadIdx.x & 63;
    int half = lane >> 5;
    int c = lane & 31;

    const float* tab = table + ((size_t)layer * TBL_ROWS) * D;
    const float* shw_l = csr_shw + layer * N_EDGES;
    int beg = rowptr[node];
    int end = rowptr[node + 1];

    float acc = 0.0f;
    for (int k = beg + half; k < end; k += 2) {
        float len = csr_len[k];
        float sw = shw_l[k];
        int s = csr_src[k];
        float tpos = fminf(len, LMAX) * ((float)TBL / LMAX);
        int i0 = (int)tpos;
        if (i0 > TBL - 1) i0 = TBL - 1;
        float f = tpos - (float)i0;
        float r0 = tab[i0 * D + c];
        float r1 = tab[i0 * D + D + c];
        float rw = r0 + f * (r1 - r0);
        float hv = hm[s * D + c];
        acc += hv * rw * sw;
    }
    acc += __shfl_down(acc, 32);  // combine the two half-wave partial sums

    if (half == 0) {
        float pre = acc + bconv[layer * D + c];
        const float* Ws = Wself + layer * D * D;
        const float* Wa = Wattr + layer * D_ATTR * D;
        const float* hrow = h + node * D;
        const float* xrow = x_attr + node * D_ATTR;
#pragma unroll
        for (int j = 0; j < D; ++j) pre += hrow[j] * Ws[j * D + c];
#pragma unroll
        for (int j = 0; j < D_ATTR; ++j) pre += xrow[j] * Wa[j * D + c];
        // all lanes' reads of hrow complete (in wave program order) before this write
        h[node * D + c] = silu(pre);
    }
}

// ---------------------------------------------------------------------------
// 8) Readout: per-node MLP scalar, segment-sum over sorted batch into out[G]
// ---------------------------------------------------------------------------
__global__ void readout_kernel(const float* __restrict__ h,
                               const int* __restrict__ batch,
                               const float* __restrict__ Wp1,
                               const float* __restrict__ bp1,
                               const float* __restrict__ Wp2,
                               const float* __restrict__ bp2,
                               float* __restrict__ out) {
    int n = blockIdx.x * blockDim.x + threadIdx.x;
    float s = 0.0f;
    int b = -1;
    if (n < N_NODES) {
        b = batch[n];
        const float* hrow = h + n * D;
        float acc2 = bp2[0];
#pragma unroll
        for (int m = 0; m < 16; ++m) {
            float a = bp1[m];
#pragma unroll
            for (int j = 0; j < D; ++j) a += hrow[j] * Wp1[j * 16 + m];
            acc2 += silu(a) * Wp2[m];
        }
        s = acc2;  // SCALE=1, SHIFT=0 baked in
    }
    unsigned long long valid = __ballot(n < N_NODES);
    if (valid == 0ull) return;
    int firstLane = __ffsll(valid) - 1;
    int b0v = __shfl(b, firstLane);
    bool ok = (b == b0v) || (n >= N_NODES);
    if (__all(ok)) {
        // batch sorted -> almost all waves uniform: one atomic per wave
#pragma unroll
        for (int o = 32; o > 0; o >>= 1) s += __shfl_down(s, o);
        if ((threadIdx.x & 63) == 0) atomicAdd(out + b0v, s);
    } else {
        if (n < N_NODES) atomicAdd(out + b, s);
    }
}

// ---------------------------------------------------------------------------
extern "C" void kernel_launch(void* const* d_in, const int* in_sizes, int n_in,
                              void* d_out, int out_size, void* d_ws, size_t ws_size,
                              hipStream_t stream) {
    const int*   x      = (const int*)d_in[0];
    const float* pos    = (const float*)d_in[1];
    const int*   eidx   = (const int*)d_in[2];
    const float* period = (const float*)d_in[3];
    const int*   batch  = (const int*)d_in[4];
    const float* W_elem = (const float*)d_in[5];
    const float* W0     = (const float*)d_in[6];
    const float* b0     = (const float*)d_in[7];
    const float* Wr1    = (const float*)d_in[8];
    const float* br1    = (const float*)d_in[9];
    const float* Wr2    = (const float*)d_in[10];
    const float* Wmsg   = (const float*)d_in[11];
    const float* Wattr  = (const float*)d_in[12];
    const float* Wself  = (const float*)d_in[13];
    const float* bconv  = (const float*)d_in[14];
    const float* wsh    = (const float*)d_in[15];
    const float* Wp1    = (const float*)d_in[16];
    const float* bp1    = (const float*)d_in[17];
    const float* Wp2    = (const float*)d_in[18];
    const float* bp2    = (const float*)d_in[19];

    char* base = (char*)d_ws;
    size_t off = 0;
    auto carve = [&](size_t bytes) -> void* {
        void* p = base + off;
        off = (off + bytes + 255) & ~(size_t)255;
        return p;
    };
    float* x_attr  = (float*)carve((size_t)N_NODES * D_ATTR * 4);
    float* h       = (float*)carve((size_t)N_NODES * D * 4);
    float* hm      = (float*)carve((size_t)N_NODES * D * 4);
    int*   csr_src = (int*)carve((size_t)N_EDGES * 4);
    float* csr_len = (float*)carve((size_t)N_EDGES * 4);
    float* csr_shw = (float*)carve((size_t)3 * N_EDGES * 4);
    int*   count   = (int*)carve((size_t)N_NODES * 4);
    int*   rowptr  = (int*)carve((size_t)(N_NODES + 1) * 4);
    int*   cursor  = (int*)carve((size_t)N_NODES * 4);
    float* table   = (float*)carve((size_t)3 * TBL_ROWS * D * 4);
    (void)ws_size; (void)in_sizes; (void)n_in; (void)out_size;

    hipMemsetAsync(count, 0, (size_t)N_NODES * 4, stream);
    hipMemsetAsync(d_out, 0, (size_t)G_GRAPHS * 4, stream);

    node_init_kernel<<<(N_NODES * 32 + 255) / 256, 256, 0, stream>>>(x, W_elem, W0, b0, x_attr, h);
    count_kernel<<<(N_EDGES + 255) / 256, 256, 0, stream>>>(eidx, count);
    scan_kernel<<<1, 1024, 0, stream>>>(count, rowptr, cursor);
    scatter_kernel<<<(N_EDGES + 255) / 256, 256, 0, stream>>>(eidx, pos, period, wsh, cursor,
                                                              csr_src, csr_len, csr_shw);
    table_kernel<<<(3 * TBL_ROWS + 127) / 128, 128, 0, stream>>>(Wr1, br1, Wr2, table);

    for (int l = 0; l < 3; ++l) {
        hm_kernel<<<(N_NODES * 32 + 255) / 256, 256, 0, stream>>>(l, h, Wmsg, hm);
        conv_kernel<<<(N_NODES * 64 + 255) / 256, 256, 0, stream>>>(
            l, hm, csr_len, csr_shw, csr_src, rowptr, x_attr, table, Wattr, Wself, bconv, h);
    }
    readout_kernel<<<(N_NODES + 255) / 256, 256, 0, stream>>>(h, batch, Wp1, bp1, Wp2, bp2,
                                                              (float*)d_out);
}

// Round 2
// 784.755 us; speedup vs baseline: 1.0259x; 1.0259x over previous
//
#include <hip/hip_runtime.h>
#include <math.h>

// Problem constants (from reference file)
constexpr int N_NODES  = 50000;
constexpr int N_EDGES  = 1600000;
constexpr int G_GRAPHS = 64;
constexpr int D        = 32;
constexpr int D_ATTR   = 16;
constexpr int N_RBF    = 8;

// rw(len) lookup table: 8192 intervals over [0, LMAX], nearest-neighbor.
// Beyond LMAX all rbf ~ exp(-2.56*25) ~ 0 so the last row is exact enough.
constexpr int   TBL      = 8192;
constexpr int   TBL_ROWS = TBL + 1;
constexpr float LMAX     = 10.0f;

__device__ __forceinline__ float silu(float x) {
    return x / (1.0f + __expf(-x));
}

// ---------------------------------------------------------------------------
// 1) Node init: x_attr = W_elem[x], h = x_attr @ W0 + b0
// ---------------------------------------------------------------------------
__global__ void node_init_kernel(const int* __restrict__ x,
                                 const float* __restrict__ W_elem,
                                 const float* __restrict__ W0,
                                 const float* __restrict__ b0,
                                 float* __restrict__ x_attr,
                                 float* __restrict__ h) {
    int t = blockIdx.x * blockDim.x + threadIdx.x;
    int n = t >> 5, c = t & 31;
    if (n >= N_NODES) return;
    int sp = x[n];
    const float* we = W_elem + sp * D_ATTR;
    float acc = b0[c];
#pragma unroll
    for (int a = 0; a < D_ATTR; ++a) acc += we[a] * W0[a * D + c];
    h[n * D + c] = acc;
    if (c < D_ATTR) x_attr[n * D_ATTR + c] = we[c];
}

// ---------------------------------------------------------------------------
// 2) Degree histogram over dst
// ---------------------------------------------------------------------------
__global__ void count_kernel(const int* __restrict__ eidx, int* __restrict__ count) {
    int e = blockIdx.x * blockDim.x + threadIdx.x;
    if (e < N_EDGES) atomicAdd(&count[eidx[N_EDGES + e]], 1);
}

// ---------------------------------------------------------------------------
// 3) Exclusive scan (single block, thread-chunked) -> rowptr, cursor
// ---------------------------------------------------------------------------
__global__ void scan_kernel(const int* __restrict__ count,
                            int* __restrict__ rowptr,
                            int* __restrict__ cursor) {
    constexpr int T = 1024;
    constexpr int CHUNK = (N_NODES + T - 1) / T;  // 49
    __shared__ int sums[T];
    int t = threadIdx.x;
    int beg = t * CHUNK;
    int local[CHUNK];
    int run = 0;
#pragma unroll
    for (int j = 0; j < CHUNK; ++j) {
        int i = beg + j;
        int v = (i < N_NODES) ? count[i] : 0;
        local[j] = run;
        run += v;
    }
    sums[t] = run;
    __syncthreads();
    for (int s = 1; s < T; s <<= 1) {
        int v = (t >= s) ? sums[t - s] : 0;
        __syncthreads();
        sums[t] += v;
        __syncthreads();
    }
    int prefix = (t == 0) ? 0 : sums[t - 1];
#pragma unroll
    for (int j = 0; j < CHUNK; ++j) {
        int i = beg + j;
        if (i < N_NODES) {
            int v = prefix + local[j];
            rowptr[i] = v;
            cursor[i] = v;
        }
    }
    if (t == T - 1) rowptr[N_NODES] = prefix + run;  // == N_EDGES
}

// ---------------------------------------------------------------------------
// 4) Edge geometry + CSR scatter: ONE packed float4 record per edge:
//    rec[k] = { __int_as_float(src), vx, vy, vz }
//    Single 16B store -> 1 cache line touched per edge (was 5).
// ---------------------------------------------------------------------------
__global__ void scatter_kernel(const int* __restrict__ eidx,
                               const float* __restrict__ pos,
                               const float* __restrict__ period,
                               int* __restrict__ cursor,
                               float4* __restrict__ rec) {
    int e = blockIdx.x * blockDim.x + threadIdx.x;
    if (e >= N_EDGES) return;
    int s = eidx[e];
    int d = eidx[N_EDGES + e];
    float vx = pos[d * 3 + 0] - pos[s * 3 + 0] + period[e * 3 + 0];
    float vy = pos[d * 3 + 1] - pos[s * 3 + 1] + period[e * 3 + 1];
    float vz = pos[d * 3 + 2] - pos[s * 3 + 2] + period[e * 3 + 2];
    int k = atomicAdd(&cursor[d], 1);
    rec[k] = make_float4(__int_as_float(s), vx, vy, vz);
}

// ---------------------------------------------------------------------------
// 5) Build rw(len) tables for the 3 layers: table[l][idx][c]
//    rw = relu(rbf @ Wr1[l] + br1[l]) @ Wr2[l]
// ---------------------------------------------------------------------------
__global__ void table_kernel(const float* __restrict__ Wr1,
                             const float* __restrict__ br1,
                             const float* __restrict__ Wr2,
                             float* __restrict__ table) {
    int t = blockIdx.x * blockDim.x + threadIdx.x;
    if (t >= 3 * TBL_ROWS) return;
    int l = t / TBL_ROWS;
    int idx = t % TBL_ROWS;
    float len = (float)idx * (LMAX / (float)TBL);
    const float gamma = (8.0f / 5.0f) * (8.0f / 5.0f);  // (N_RBF/CUTOFF)^2
    float rbf[N_RBF];
#pragma unroll
    for (int k = 0; k < N_RBF; ++k) {
        float dd = len - (float)k * (5.0f / 7.0f);  // linspace(0, CUTOFF, 8)
        rbf[k] = __expf(-gamma * dd * dd);
    }
    float out[D];
#pragma unroll
    for (int c = 0; c < D; ++c) out[c] = 0.0f;
    for (int j = 0; j < D; ++j) {
        float z = br1[l * D + j];
#pragma unroll
        for (int k = 0; k < N_RBF; ++k) z += rbf[k] * Wr1[l * N_RBF * D + k * D + j];
        z = fmaxf(z, 0.0f);
        const float* w2 = Wr2 + l * D * D + j * D;
#pragma unroll
        for (int c = 0; c < D; ++c) out[c] += z * w2[c];
    }
    float* dst = table + ((size_t)(l * TBL_ROWS + idx)) * D;
#pragma unroll
    for (int c = 0; c < D; ++c) dst[c] = out[c];
}

// ---------------------------------------------------------------------------
// 6) hm = h @ Wmsg[l]
// ---------------------------------------------------------------------------
__global__ void hm_kernel(int layer,
                          const float* __restrict__ h,
                          const float* __restrict__ Wmsg,
                          float* __restrict__ hm) {
    int t = blockIdx.x * blockDim.x + threadIdx.x;
    int n = t >> 5, c = t & 31;
    if (n >= N_NODES) return;
    const float* W = Wmsg + layer * D * D;
    const float* hrow = h + n * D;
    float acc = 0.0f;
#pragma unroll
    for (int j = 0; j < D; ++j) acc += hrow[j] * W[j * D + c];
    hm[n * D + c] = acc;
}

// ---------------------------------------------------------------------------
// 7) Conv layer: wave-per-node, channel-parallel; fused node update.
//    lane = {half, c}; the two half-waves each process one edge/iteration.
//    Per edge: 1 broadcast float4 rec, 1 table-row gather (nearest), 1 hm-row
//    gather; len/sh_w recomputed in-register from v and wsh.
// ---------------------------------------------------------------------------
__global__ void conv_kernel(int layer,
                            const float* __restrict__ hm,
                            const float4* __restrict__ rec,
                            const int* __restrict__ rowptr,
                            const float* __restrict__ x_attr,
                            const float* __restrict__ table,
                            const float* __restrict__ wsh,
                            const float* __restrict__ Wattr,
                            const float* __restrict__ Wself,
                            const float* __restrict__ bconv,
                            float* __restrict__ h) {
    int gtid = blockIdx.x * blockDim.x + threadIdx.x;
    int node = gtid >> 6;
    if (node >= N_NODES) return;
    int lane = threadIdx.x & 63;
    int half = lane >> 5;
    int c = lane & 31;

    // wsh row for this layer (wave-uniform scalar loads)
    float w0 = wsh[layer * 4 + 0];
    float w1 = wsh[layer * 4 + 1];
    float w2 = wsh[layer * 4 + 2];
    float w3 = wsh[layer * 4 + 3];

    const float* tab = table + ((size_t)layer * TBL_ROWS) * D;
    int beg = rowptr[node];
    int end = rowptr[node + 1];

    float acc = 0.0f;
    for (int k = beg + half; k < end; k += 2) {
        float4 r = rec[k];
        int s = __float_as_int(r.x);
        float vx = r.y, vy = r.z, vz = r.w;
        float len = sqrtf(vx * vx + vy * vy + vz * vz);
        float inv = 1.0f / (len + 1e-9f);
        float sw = w0 + (vx * w1 + vy * w2 + vz * w3) * inv;
        int idx = (int)fminf(len * ((float)TBL / LMAX) + 0.5f, (float)TBL);
        float rw = tab[idx * D + c];
        acc = fmaf(hm[s * D + c], rw * sw, acc);
    }
    acc += __shfl_down(acc, 32);  // combine the two half-wave partial sums

    if (half == 0) {
        float pre = acc + bconv[layer * D + c];
        const float* Ws = Wself + layer * D * D;
        const float* Wa = Wattr + layer * D_ATTR * D;
        const float* hrow = h + node * D;
        const float* xrow = x_attr + node * D_ATTR;
#pragma unroll
        for (int j = 0; j < D; ++j) pre += hrow[j] * Ws[j * D + c];
#pragma unroll
        for (int j = 0; j < D_ATTR; ++j) pre += xrow[j] * Wa[j * D + c];
        h[node * D + c] = silu(pre);
    }
}

// ---------------------------------------------------------------------------
// 8) Readout: per-node MLP scalar, segment-sum over sorted batch into out[G]
// ---------------------------------------------------------------------------
__global__ void readout_kernel(const float* __restrict__ h,
                               const int* __restrict__ batch,
                               const float* __restrict__ Wp1,
                               const float* __restrict__ bp1,
                               const float* __restrict__ Wp2,
                               const float* __restrict__ bp2,
                               float* __restrict__ out) {
    int n = blockIdx.x * blockDim.x + threadIdx.x;
    float s = 0.0f;
    int b = -1;
    if (n < N_NODES) {
        b = batch[n];
        const float* hrow = h + n * D;
        float acc2 = bp2[0];
#pragma unroll
        for (int m = 0; m < 16; ++m) {
            float a = bp1[m];
#pragma unroll
            for (int j = 0; j < D; ++j) a += hrow[j] * Wp1[j * 16 + m];
            acc2 += silu(a) * Wp2[m];
        }
        s = acc2;  // SCALE=1, SHIFT=0 baked in
    }
    unsigned long long valid = __ballot(n < N_NODES);
    if (valid == 0ull) return;
    int firstLane = __ffsll(valid) - 1;
    int b0v = __shfl(b, firstLane);
    bool ok = (b == b0v) || (n >= N_NODES);
    if (__all(ok)) {
#pragma unroll
        for (int o = 32; o > 0; o >>= 1) s += __shfl_down(s, o);
        if ((threadIdx.x & 63) == 0) atomicAdd(out + b0v, s);
    } else {
        if (n < N_NODES) atomicAdd(out + b, s);
    }
}

// ---------------------------------------------------------------------------
extern "C" void kernel_launch(void* const* d_in, const int* in_sizes, int n_in,
                              void* d_out, int out_size, void* d_ws, size_t ws_size,
                              hipStream_t stream) {
    const int*   x      = (const int*)d_in[0];
    const float* pos    = (const float*)d_in[1];
    const int*   eidx   = (const int*)d_in[2];
    const float* period = (const float*)d_in[3];
    const int*   batch  = (const int*)d_in[4];
    const float* W_elem = (const float*)d_in[5];
    const float* W0     = (const float*)d_in[6];
    const float* b0     = (const float*)d_in[7];
    const float* Wr1    = (const float*)d_in[8];
    const float* br1    = (const float*)d_in[9];
    const float* Wr2    = (const float*)d_in[10];
    const float* Wmsg   = (const float*)d_in[11];
    const float* Wattr  = (const float*)d_in[12];
    const float* Wself  = (const float*)d_in[13];
    const float* bconv  = (const float*)d_in[14];
    const float* wsh    = (const float*)d_in[15];
    const float* Wp1    = (const float*)d_in[16];
    const float* bp1    = (const float*)d_in[17];
    const float* Wp2    = (const float*)d_in[18];
    const float* bp2    = (const float*)d_in[19];

    char* base = (char*)d_ws;
    size_t off = 0;
    auto carve = [&](size_t bytes) -> void* {
        void* p = base + off;
        off = (off + bytes + 255) & ~(size_t)255;
        return p;
    };
    float*  x_attr = (float*)carve((size_t)N_NODES * D_ATTR * 4);
    float*  h      = (float*)carve((size_t)N_NODES * D * 4);
    float*  hm     = (float*)carve((size_t)N_NODES * D * 4);
    float4* rec    = (float4*)carve((size_t)N_EDGES * 16);
    int*    count  = (int*)carve((size_t)N_NODES * 4);
    int*    rowptr = (int*)carve((size_t)(N_NODES + 1) * 4);
    int*    cursor = (int*)carve((size_t)N_NODES * 4);
    float*  table  = (float*)carve((size_t)3 * TBL_ROWS * D * 4);
    (void)ws_size; (void)in_sizes; (void)n_in; (void)out_size;

    hipMemsetAsync(count, 0, (size_t)N_NODES * 4, stream);
    hipMemsetAsync(d_out, 0, (size_t)G_GRAPHS * 4, stream);

    node_init_kernel<<<(N_NODES * 32 + 255) / 256, 256, 0, stream>>>(x, W_elem, W0, b0, x_attr, h);
    count_kernel<<<(N_EDGES + 255) / 256, 256, 0, stream>>>(eidx, count);
    scan_kernel<<<1, 1024, 0, stream>>>(count, rowptr, cursor);
    scatter_kernel<<<(N_EDGES + 255) / 256, 256, 0, stream>>>(eidx, pos, period, cursor, rec);
    table_kernel<<<(3 * TBL_ROWS + 127) / 128, 128, 0, stream>>>(Wr1, br1, Wr2, table);

    for (int l = 0; l < 3; ++l) {
        hm_kernel<<<(N_NODES * 32 + 255) / 256, 256, 0, stream>>>(l, h, Wmsg, hm);
        conv_kernel<<<(N_NODES * 64 + 255) / 256, 256, 0, stream>>>(
            l, hm, rec, rowptr, x_attr, table, wsh, Wattr, Wself, bconv, h);
    }
    readout_kernel<<<(N_NODES + 255) / 256, 256, 0, stream>>>(h, batch, Wp1, bp1, Wp2, bp2,
                                                              (float*)d_out);
}

// Round 3
// 656.171 us; speedup vs baseline: 1.2269x; 1.1960x over previous
//
#include <hip/hip_runtime.h>
#include <math.h>

// Problem constants (from reference file)
constexpr int N_NODES  = 50000;
constexpr int N_EDGES  = 1600000;
constexpr int G_GRAPHS = 64;
constexpr int D        = 32;
constexpr int D_ATTR   = 16;
constexpr int N_RBF    = 8;

// rw(len) lookup table: 8192 intervals over [0, LMAX], nearest-neighbor.
constexpr int   TBL      = 8192;
constexpr int   TBL_ROWS = TBL + 1;
constexpr float LMAX     = 10.0f;

__device__ __forceinline__ float silu(float x) {
    return x / (1.0f + __expf(-x));
}

// ---------------------------------------------------------------------------
// 1) Node init: x_attr = W_elem[x], h = x_attr@W0 + b0, hm0 = h@Wmsg[0]
//    32 threads per node (2 nodes per wave); hm via width-32 shfl broadcast.
// ---------------------------------------------------------------------------
__global__ void node_init_kernel(const int* __restrict__ x,
                                 const float* __restrict__ W_elem,
                                 const float* __restrict__ W0,
                                 const float* __restrict__ b0,
                                 const float* __restrict__ Wmsg0,
                                 float* __restrict__ x_attr,
                                 float* __restrict__ h,
                                 float* __restrict__ hm) {
    int t = blockIdx.x * blockDim.x + threadIdx.x;
    int n = t >> 5, c = t & 31;
    if (n >= N_NODES) return;
    int sp = x[n];
    const float* we = W_elem + sp * D_ATTR;
    float acc = b0[c];
#pragma unroll
    for (int a = 0; a < D_ATTR; ++a) acc += we[a] * W0[a * D + c];
    h[n * D + c] = acc;
    if (c < D_ATTR) x_attr[n * D_ATTR + c] = we[c];
    // hm0[n][c] = sum_j h[n][j] * Wmsg0[j][c]  (h row lives across the 32 lanes)
    float m = 0.0f;
#pragma unroll
    for (int j = 0; j < D; ++j) {
        float hj = __shfl(acc, j, 32);
        m = fmaf(hj, Wmsg0[j * D + c], m);
    }
    hm[n * D + c] = m;
}

// ---------------------------------------------------------------------------
// 2) Degree histogram over dst
// ---------------------------------------------------------------------------
__global__ void count_kernel(const int* __restrict__ eidx, int* __restrict__ count) {
    int e = blockIdx.x * blockDim.x + threadIdx.x;
    if (e < N_EDGES) atomicAdd(&count[eidx[N_EDGES + e]], 1);
}

// ---------------------------------------------------------------------------
// 3) Exclusive scan (single block, thread-chunked) -> rowptr, cursor
// ---------------------------------------------------------------------------
__global__ void scan_kernel(const int* __restrict__ count,
                            int* __restrict__ rowptr,
                            int* __restrict__ cursor) {
    constexpr int T = 1024;
    constexpr int CHUNK = (N_NODES + T - 1) / T;  // 49
    __shared__ int sums[T];
    int t = threadIdx.x;
    int beg = t * CHUNK;
    int local[CHUNK];
    int run = 0;
#pragma unroll
    for (int j = 0; j < CHUNK; ++j) {
        int i = beg + j;
        int v = (i < N_NODES) ? count[i] : 0;
        local[j] = run;
        run += v;
    }
    sums[t] = run;
    __syncthreads();
    for (int s = 1; s < T; s <<= 1) {
        int v = (t >= s) ? sums[t - s] : 0;
        __syncthreads();
        sums[t] += v;
        __syncthreads();
    }
    int prefix = (t == 0) ? 0 : sums[t - 1];
#pragma unroll
    for (int j = 0; j < CHUNK; ++j) {
        int i = beg + j;
        if (i < N_NODES) {
            int v = prefix + local[j];
            rowptr[i] = v;
            cursor[i] = v;
        }
    }
    if (t == T - 1) rowptr[N_NODES] = prefix + run;  // == N_EDGES
}

// ---------------------------------------------------------------------------
// 4) Edge geometry + CSR scatter. ALL edge-invariant math done here (this
//    kernel is scatter-write-bound, VALU ~2% -> free). One float4 per edge:
//    rec[k] = { __int_as_float(src | (tbl_idx<<16)), sw_l0, sw_l1, sw_l2 }
// ---------------------------------------------------------------------------
__global__ void scatter_kernel(const int* __restrict__ eidx,
                               const float* __restrict__ pos,
                               const float* __restrict__ period,
                               const float* __restrict__ wsh,
                               int* __restrict__ cursor,
                               float4* __restrict__ rec) {
    int e = blockIdx.x * blockDim.x + threadIdx.x;
    if (e >= N_EDGES) return;
    int s = eidx[e];
    int d = eidx[N_EDGES + e];
    float vx = pos[d * 3 + 0] - pos[s * 3 + 0] + period[e * 3 + 0];
    float vy = pos[d * 3 + 1] - pos[s * 3 + 1] + period[e * 3 + 1];
    float vz = pos[d * 3 + 2] - pos[s * 3 + 2] + period[e * 3 + 2];
    float len = sqrtf(vx * vx + vy * vy + vz * vz);
    float inv = 1.0f / (len + 1e-9f);
    int idx = (int)fminf(len * ((float)TBL / LMAX) + 0.5f, (float)TBL);
    float sw[3];
#pragma unroll
    for (int l = 0; l < 3; ++l)
        sw[l] = wsh[l * 4 + 0] + (vx * wsh[l * 4 + 1] + vy * wsh[l * 4 + 2] + vz * wsh[l * 4 + 3]) * inv;
    int k = atomicAdd(&cursor[d], 1);
    rec[k] = make_float4(__int_as_float(s | (idx << 16)), sw[0], sw[1], sw[2]);
}

// ---------------------------------------------------------------------------
// 5) Build rw(len) tables for the 3 layers: table[l][idx][c]
// ---------------------------------------------------------------------------
__global__ void table_kernel(const float* __restrict__ Wr1,
                             const float* __restrict__ br1,
                             const float* __restrict__ Wr2,
                             float* __restrict__ table) {
    int t = blockIdx.x * blockDim.x + threadIdx.x;
    if (t >= 3 * TBL_ROWS) return;
    int l = t / TBL_ROWS;
    int idx = t % TBL_ROWS;
    float len = (float)idx * (LMAX / (float)TBL);
    const float gamma = (8.0f / 5.0f) * (8.0f / 5.0f);  // (N_RBF/CUTOFF)^2
    float rbf[N_RBF];
#pragma unroll
    for (int k = 0; k < N_RBF; ++k) {
        float dd = len - (float)k * (5.0f / 7.0f);  // linspace(0, CUTOFF, 8)
        rbf[k] = __expf(-gamma * dd * dd);
    }
    float out[D];
#pragma unroll
    for (int c = 0; c < D; ++c) out[c] = 0.0f;
    for (int j = 0; j < D; ++j) {
        float z = br1[l * D + j];
#pragma unroll
        for (int k = 0; k < N_RBF; ++k) z += rbf[k] * Wr1[l * N_RBF * D + k * D + j];
        z = fmaxf(z, 0.0f);
        const float* w2 = Wr2 + l * D * D + j * D;
#pragma unroll
        for (int c = 0; c < D; ++c) out[c] += z * w2[c];
    }
    float* dst = table + ((size_t)(l * TBL_ROWS + idx)) * D;
#pragma unroll
    for (int c = 0; c < D; ++c) dst[c] = out[c];
}

// ---------------------------------------------------------------------------
// 6) Conv layer (templated): wave-per-node, lane = {half, c}; the two
//    half-waves each own alternating CSR slots, unrolled x2 (4 edges in
//    flight). Fused epilogue: h update + hm_next = h@Wmsg[LAYER+1].
// ---------------------------------------------------------------------------
template <int LAYER, bool WRITE_HM>
__global__ void conv_kernel(const float* __restrict__ hm,
                            const float4* __restrict__ rec,
                            const int* __restrict__ rowptr,
                            const float* __restrict__ x_attr,
                            const float* __restrict__ table,
                            const float* __restrict__ Wattr,
                            const float* __restrict__ Wself,
                            const float* __restrict__ bconv,
                            const float* __restrict__ Wmsg_next,
                            float* __restrict__ h,
                            float* __restrict__ hm_next) {
    int gtid = blockIdx.x * blockDim.x + threadIdx.x;
    int node = gtid >> 6;
    if (node >= N_NODES) return;
    int lane = threadIdx.x & 63;
    int half = lane >> 5;
    int c = lane & 31;

    const float* tab = table + ((size_t)LAYER * TBL_ROWS) * D;
    int beg = rowptr[node];
    int end = rowptr[node + 1];

    float acc0 = 0.0f, acc1 = 0.0f;
    int k = beg + half;
    for (; k + 2 < end; k += 4) {
        float4 r0 = rec[k];
        float4 r1 = rec[k + 2];
        int p0 = __float_as_int(r0.x);
        int p1 = __float_as_int(r1.x);
        int s0 = p0 & 0xFFFF, i0 = p0 >> 16;
        int s1 = p1 & 0xFFFF, i1 = p1 >> 16;
        float sw0 = (LAYER == 0) ? r0.y : (LAYER == 1) ? r0.z : r0.w;
        float sw1 = (LAYER == 0) ? r1.y : (LAYER == 1) ? r1.z : r1.w;
        float rw0 = tab[i0 * D + c];
        float rw1 = tab[i1 * D + c];
        float hv0 = hm[s0 * D + c];
        float hv1 = hm[s1 * D + c];
        acc0 = fmaf(hv0, rw0 * sw0, acc0);
        acc1 = fmaf(hv1, rw1 * sw1, acc1);
    }
    for (; k < end; k += 2) {
        float4 r = rec[k];
        int p = __float_as_int(r.x);
        int s = p & 0xFFFF, i = p >> 16;
        float sw = (LAYER == 0) ? r.y : (LAYER == 1) ? r.z : r.w;
        acc0 = fmaf(hm[s * D + c], tab[i * D + c] * sw, acc0);
    }
    float acc = acc0 + acc1;
    acc += __shfl_down(acc, 32);  // combine the two half-wave partial sums

    if (half == 0) {
        float pre = acc + bconv[LAYER * D + c];
        const float* Ws = Wself + LAYER * D * D;
        const float* Wa = Wattr + LAYER * D_ATTR * D;
        const float* hrow = h + node * D;
        const float* xrow = x_attr + node * D_ATTR;
#pragma unroll
        for (int j = 0; j < D; ++j) pre += hrow[j] * Ws[j * D + c];
#pragma unroll
        for (int j = 0; j < D_ATTR; ++j) pre += xrow[j] * Wa[j * D + c];
        float hn = silu(pre);
        h[node * D + c] = hn;
        if (WRITE_HM) {
            // hm_next[node][c] = sum_j hn[j] * Wmsg_next[j][c], row in lanes 0..31
            float m = 0.0f;
#pragma unroll
            for (int j = 0; j < D; ++j) {
                float hj = __shfl(hn, j);
                m = fmaf(hj, Wmsg_next[j * D + c], m);
            }
            hm_next[node * D + c] = m;
        }
    }
}

// ---------------------------------------------------------------------------
// 7) Readout: per-node MLP scalar, segment-sum over sorted batch into out[G]
// ---------------------------------------------------------------------------
__global__ void readout_kernel(const float* __restrict__ h,
                               const int* __restrict__ batch,
                               const float* __restrict__ Wp1,
                               const float* __restrict__ bp1,
                               const float* __restrict__ Wp2,
                               const float* __restrict__ bp2,
                               float* __restrict__ out) {
    int n = blockIdx.x * blockDim.x + threadIdx.x;
    float s = 0.0f;
    int b = -1;
    if (n < N_NODES) {
        b = batch[n];
        const float* hrow = h + n * D;
        float acc2 = bp2[0];
#pragma unroll
        for (int m = 0; m < 16; ++m) {
            float a = bp1[m];
#pragma unroll
            for (int j = 0; j < D; ++j) a += hrow[j] * Wp1[j * 16 + m];
            acc2 += silu(a) * Wp2[m];
        }
        s = acc2;  // SCALE=1, SHIFT=0 baked in
    }
    unsigned long long valid = __ballot(n < N_NODES);
    if (valid == 0ull) return;
    int firstLane = __ffsll(valid) - 1;
    int b0v = __shfl(b, firstLane);
    bool ok = (b == b0v) || (n >= N_NODES);
    if (__all(ok)) {
#pragma unroll
        for (int o = 32; o > 0; o >>= 1) s += __shfl_down(s, o);
        if ((threadIdx.x & 63) == 0) atomicAdd(out + b0v, s);
    } else {
        if (n < N_NODES) atomicAdd(out + b, s);
    }
}

// ---------------------------------------------------------------------------
extern "C" void kernel_launch(void* const* d_in, const int* in_sizes, int n_in,
                              void* d_out, int out_size, void* d_ws, size_t ws_size,
                              hipStream_t stream) {
    const int*   x      = (const int*)d_in[0];
    const float* pos    = (const float*)d_in[1];
    const int*   eidx   = (const int*)d_in[2];
    const float* period = (const float*)d_in[3];
    const int*   batch  = (const int*)d_in[4];
    const float* W_elem = (const float*)d_in[5];
    const float* W0     = (const float*)d_in[6];
    const float* b0     = (const float*)d_in[7];
    const float* Wr1    = (const float*)d_in[8];
    const float* br1    = (const float*)d_in[9];
    const float* Wr2    = (const float*)d_in[10];
    const float* Wmsg   = (const float*)d_in[11];
    const float* Wattr  = (const float*)d_in[12];
    const float* Wself  = (const float*)d_in[13];
    const float* bconv  = (const float*)d_in[14];
    const float* wsh    = (const float*)d_in[15];
    const float* Wp1    = (const float*)d_in[16];
    const float* bp1    = (const float*)d_in[17];
    const float* Wp2    = (const float*)d_in[18];
    const float* bp2    = (const float*)d_in[19];

    char* base = (char*)d_ws;
    size_t off = 0;
    auto carve = [&](size_t bytes) -> void* {
        void* p = base + off;
        off = (off + bytes + 255) & ~(size_t)255;
        return p;
    };
    float*  x_attr = (float*)carve((size_t)N_NODES * D_ATTR * 4);
    float*  h      = (float*)carve((size_t)N_NODES * D * 4);
    float*  hm_a   = (float*)carve((size_t)N_NODES * D * 4);
    float*  hm_b   = (float*)carve((size_t)N_NODES * D * 4);
    float4* rec    = (float4*)carve((size_t)N_EDGES * 16);
    int*    count  = (int*)carve((size_t)N_NODES * 4);
    int*    rowptr = (int*)carve((size_t)(N_NODES + 1) * 4);
    int*    cursor = (int*)carve((size_t)N_NODES * 4);
    float*  table  = (float*)carve((size_t)3 * TBL_ROWS * D * 4);
    (void)ws_size; (void)in_sizes; (void)n_in; (void)out_size;

    hipMemsetAsync(count, 0, (size_t)N_NODES * 4, stream);
    hipMemsetAsync(d_out, 0, (size_t)G_GRAPHS * 4, stream);

    node_init_kernel<<<(N_NODES * 32 + 255) / 256, 256, 0, stream>>>(
        x, W_elem, W0, b0, Wmsg + 0 * D * D, x_attr, h, hm_a);
    count_kernel<<<(N_EDGES + 255) / 256, 256, 0, stream>>>(eidx, count);
    scan_kernel<<<1, 1024, 0, stream>>>(count, rowptr, cursor);
    scatter_kernel<<<(N_EDGES + 255) / 256, 256, 0, stream>>>(eidx, pos, period, wsh, cursor, rec);
    table_kernel<<<(3 * TBL_ROWS + 127) / 128, 128, 0, stream>>>(Wr1, br1, Wr2, table);

    int cgrid = (N_NODES * 64 + 255) / 256;
    conv_kernel<0, true><<<cgrid, 256, 0, stream>>>(hm_a, rec, rowptr, x_attr, table,
                                                    Wattr, Wself, bconv, Wmsg + 1 * D * D, h, hm_b);
    conv_kernel<1, true><<<cgrid, 256, 0, stream>>>(hm_b, rec, rowptr, x_attr, table,
                                                    Wattr, Wself, bconv, Wmsg + 2 * D * D, h, hm_a);
    conv_kernel<2, false><<<cgrid, 256, 0, stream>>>(hm_a, rec, rowptr, x_attr, table,
                                                     Wattr, Wself, bconv, nullptr, h, nullptr);

    readout_kernel<<<(N_NODES + 255) / 256, 256, 0, stream>>>(h, batch, Wp1, bp1, Wp2, bp2,
                                                              (float*)d_out);
}